// Round 4
// baseline (309.924 us; speedup 1.0000x reference)
//
#include <hip/hip_runtime.h>
#include <hip/hip_bf16.h>

// ---------------------------------------------------------------------------
// FCx2DetHead pipeline. R11: B reg-staged -> bf16 LDS (kills per-wave f2bf
// repack: each B element converted once, not 4x), 40 KB LDS -> 4 blocks/CU.
// Plus fusions: reduce(G2)+fc_small -> fc_small_red, reduce(G5)+head ->
// head_red (13 -> 11 dispatches, h2/h4 round-trips removed).
//  - A staging via global_load_lds (16B) unchanged; 2-phase m97-style loop.
//  - B: global_load_dwordx4 x2 (next k-step) issued before compute(cur),
//    f2bf+ds_write_b128 after compute, __syncthreads covers both paths.
//  - XOR swizzles: A unit sl=quad^((r>>1)&3); B bf16 same geometry (2-way=free).
// ---------------------------------------------------------------------------

#define NROI 256
#define NB   8
#define INF  12544   // 256*49
#define DFC  1024
#define FCC  512

typedef __attribute__((ext_vector_type(8))) short short8;
typedef __attribute__((ext_vector_type(4))) float floatx4;

static __device__ __forceinline__ unsigned short f2bf(float f) {
    unsigned int u = __float_as_uint(f);
    unsigned int r = (u + 0x7fffu + ((u >> 16) & 1u)) >> 16;
    return (unsigned short)r;
}

static __device__ __forceinline__ void async_copy16(const void* g, void* l) {
    __builtin_amdgcn_global_load_lds(
        (const __attribute__((address_space(1))) unsigned int*)g,
        (__attribute__((address_space(3))) unsigned int*)l, 16, 0, 0);
}

// ---------------- transpose x (B,C,H,W) -> feat (B,H,W,C) -------------------
__global__ __launch_bounds__(256) void transpose_kernel(
        const float* __restrict__ x, float* __restrict__ xT) {
    __shared__ float t[32][33];
    int b  = blockIdx.z;
    int cb = blockIdx.y * 32;     // channel tile
    int lb = blockIdx.x * 32;     // hw tile (0..624)
    int tx = threadIdx.x & 31, ty = threadIdx.x >> 5;
#pragma unroll
    for (int r = 0; r < 4; ++r) {
        int c = cb + ty + r * 8, l = lb + tx;
        if (l < 625) t[ty + r * 8][tx] = x[(size_t)(b * 256 + c) * 625 + l];
    }
    __syncthreads();
#pragma unroll
    for (int r = 0; r < 4; ++r) {
        int l = lb + ty + r * 8, c = cb + tx;
        if (l < 625) xT[((size_t)b * 625 + l) * 256 + c] = t[tx][ty + r * 8];
    }
}

// ---------------- fused deformable RoI pool (prep + gather) -----------------
__global__ __launch_bounds__(256) void pool_kernel(
        const float* __restrict__ feat, const float* __restrict__ rois,
        const float* __restrict__ off, int has_off,
        unsigned short* __restrict__ P) {
    __shared__ float sGrid[49][16];
    __shared__ int   sBase[49];
    __shared__ unsigned short sOut[128 * 49];
    const float SSC = (float)(25.0 / 255.0);
    int q = blockIdx.x;            // channel half
    int n = blockIdx.y;            // roi
    int tid = threadIdx.x;

    if (tid < 49) {
        int bin = tid;
        const float* r = rois + n * 5;
        int b = (int)r[0];
        float sw = rintf(r[1]) * SSC - 0.5f;
        float sh = rintf(r[2]) * SSC - 0.5f;
        float rw = fmaxf((rintf(r[3]) + 1.0f) * SSC - 0.5f - sw, 0.1f);
        float rh = fmaxf((rintf(r[4]) + 1.0f) * SSC - 0.5f - sh, 0.1f);
        float bw = rw / 7.0f, bh = rh / 7.0f;
        float bws = bw * 0.25f, bhs = bh * 0.25f;
        int ph = bin / 7, pw = bin - ph * 7;
        float tx = 0.f, ty = 0.f;
        if (has_off) {
            tx = off[n * 98 + bin] * 0.1f;
            ty = off[n * 98 + 49 + bin] * 0.1f;
        }
        float wstart = pw * bw + sw + tx * rw;
        float hstart = ph * bh + sh + ty * rh;
#pragma unroll
        for (int i = 0; i < 16; ++i) sGrid[bin][i] = 0.f;
        int gy0 = 0, gx0 = 0, cnt = 0;
#pragma unroll
        for (int s = 0; s < 16; ++s) {
            float fx = wstart + (s & 3) * bws;
            float fy = hstart + (s >> 2) * bhs;
            bool valid = (fx >= -0.5f) && (fx <= 24.5f) && (fy >= -0.5f) && (fy <= 24.5f);
            float xc = fminf(fmaxf(fx, 0.f), 24.f);
            float yc = fminf(fmaxf(fy, 0.f), 24.f);
            float x0f = floorf(xc), y0f = floorf(yc);
            float dx = xc - x0f, dy = yc - y0f;
            int x0 = (int)x0f, y0 = (int)y0f;
            int x1 = (int)ceilf(xc), y1 = (int)ceilf(yc);
            if (s == 0) { gy0 = y0; gx0 = x0; }
            float w00 = (1.f - dx) * (1.f - dy), w01 = dx * (1.f - dy);
            float w10 = (1.f - dx) * dy,         w11 = dx * dy;
            if (!valid) { w00 = w01 = w10 = w11 = 0.f; }
            cnt += valid ? 1 : 0;
            int ry0 = (y0 - gy0) * 4, ry1 = (y1 - gy0) * 4;
            sGrid[bin][ry0 + (x0 - gx0)] += w00;
            sGrid[bin][ry0 + (x1 - gx0)] += w01;
            sGrid[bin][ry1 + (x0 - gx0)] += w10;
            sGrid[bin][ry1 + (x1 - gx0)] += w11;
        }
        float inv = 1.0f / fmaxf((float)cnt, 1.0f);
#pragma unroll
        for (int i = 0; i < 16; ++i) sGrid[bin][i] *= inv;
        sBase[bin] = gy0 | (gx0 << 8) | (b << 16);
    }
    __syncthreads();

    int wv = tid >> 6, lane = tid & 63;
    int cbase = q * 128 + lane * 2;
    for (int bin = wv; bin < 49; bin += 4) {
        int base = sBase[bin];
        int gy0 = base & 255, gx0 = (base >> 8) & 255, b = base >> 16;
        const float4* wp = (const float4*)sGrid[bin];
        float4 w0 = wp[0], w1 = wp[1], w2 = wp[2], w3 = wp[3];
        float ww[16] = { w0.x, w0.y, w0.z, w0.w, w1.x, w1.y, w1.z, w1.w,
                         w2.x, w2.y, w2.z, w2.w, w3.x, w3.y, w3.z, w3.w };
        int rowOff[4], colOff[4];
#pragma unroll
        for (int r = 0; r < 4; ++r) {
            rowOff[r] = min(gy0 + r, 24) * 25;
            colOff[r] = min(gx0 + r, 24);
        }
        int b625 = b * 625;
        float ax = 0.f, ay = 0.f;
#pragma unroll
        for (int cell = 0; cell < 16; ++cell) {
            int pix = b625 + rowOff[cell >> 2] + colOff[cell & 3];
            float2 v = *(const float2*)(feat + (size_t)pix * 256 + cbase);
            ax += ww[cell] * v.x;
            ay += ww[cell] * v.y;
        }
        sOut[(lane * 2) * 49 + bin] = f2bf(ax);
        sOut[(lane * 2 + 1) * 49 + bin] = f2bf(ay);
    }
    __syncthreads();
    const uint2* so = (const uint2*)sOut;
    uint2* dp = (uint2*)(P + (size_t)n * INF + q * 128 * 49);
    for (int i = tid; i < 128 * 49 / 4; i += 256) dp[i] = so[i];
}

// ---------------- 2-phase MFMA GEMM (BM=256=M, BN=64) -> fp32 partials ------
// STAGE(next) -> compute(cur) -> __syncthreads. A via 4x global_load_lds 16B.
// B via reg-stage: 2x global_load_dwordx4 (issued pre-compute), f2bf once,
// ds_write_b128 (post-compute). B lives in LDS as bf16 (4 KB/slot).
// 40 KB LDS total -> 4 blocks/CU.
__global__ __launch_bounds__(256) void gemm_pipe(
        const unsigned short* __restrict__ A, const float* __restrict__ Bw,
        float* __restrict__ Cpart, int N, int K, int kSteps) {
    constexpr int BM = 256, BN = 64;
    constexpr int FM = 4, FN = 4;
    __shared__ unsigned short As[2][BM * 32];  // 16 KB / slot
    __shared__ unsigned short Bs[2][BN * 32];  //  4 KB / slot (bf16)
    const int tid = threadIdx.x;
    const int lane = tid & 63;
    const int wave = tid >> 6;
    const int n0 = blockIdx.x * BN;
    const int k0 = blockIdx.z * kSteps * 32;
    const int quad = lane >> 4;
    const int l16 = lane & 15;

    floatx4 acc[FM][FN];
#pragma unroll
    for (int i = 0; i < FM; ++i)
#pragma unroll
        for (int j = 0; j < FN; ++j) acc[i][j] = (floatx4)0.f;

    // A staging: thread t, copy i -> LDS 16B-unit (i*256 + t)
    const unsigned short* ag[4];
    int albase[4];
#pragma unroll
    for (int i = 0; i < 4; ++i) {
        int idx = tid + i * 256;
        int row = idx >> 2;
        int kg4 = (idx & 3) ^ ((row >> 1) & 3);
        ag[i] = A + (size_t)row * K + kg4 * 8;
        albase[i] = (i * 256 + wave * 64) * 16;   // wave-uniform byte base
    }
    // B reg-staging: thread t owns LDS 16B-unit t = (row=t>>2, kg=t&3);
    // global k-granule = kg ^ ((row>>1)&3) (same swizzle the reader undoes).
    const int brow = tid >> 2;
    const int bkg  = (tid & 3) ^ ((brow >> 1) & 3);
    const float* bgp = Bw + (size_t)(n0 + brow) * K + bkg * 8;
    unsigned short* const bl0 = &Bs[0][tid * 8];
    unsigned short* const bl1 = &Bs[1][tid * 8];

    auto issueA = [&](int slot, int kk) {
#pragma unroll
        for (int i = 0; i < 4; ++i)
            async_copy16(ag[i] + kk, (char*)&As[slot][0] + albase[i]);
    };
    auto packB = [&](float4 v0, float4 v1) {
        short8 w;
        w[0] = (short)f2bf(v0.x); w[1] = (short)f2bf(v0.y);
        w[2] = (short)f2bf(v0.z); w[3] = (short)f2bf(v0.w);
        w[4] = (short)f2bf(v1.x); w[5] = (short)f2bf(v1.y);
        w[6] = (short)f2bf(v1.z); w[7] = (short)f2bf(v1.w);
        return w;
    };

    // prologue: stage k-step 0 into slot 0
    issueA(0, k0);
    {
        float4 v0 = *(const float4*)(bgp + k0);
        float4 v1 = *(const float4*)(bgp + k0 + 4);
        *(short8*)bl0 = packB(v0, v1);
    }
    __syncthreads();

    int cur = 0;
    for (int ks = 0; ks < kSteps; ++ks) {
        const bool hn = (ks + 1 < kSteps);
        const int kn = k0 + (ks + 1) * 32;
        float4 v0, v1;
        if (hn) {
            issueA(cur ^ 1, kn);          // A direct-to-LDS (next slot)
            v0 = *(const float4*)(bgp + kn);   // B -> regs (latency under MFMA)
            v1 = *(const float4*)(bgp + kn + 4);
        }
        // fragments from slot cur
        short8 a[FM], bf[FN];
#pragma unroll
        for (int i = 0; i < FM; ++i) {
            int r = wave * 64 + i * 16 + l16;
            int sl = quad ^ ((r >> 1) & 3);
            a[i] = *(const short8*)(&As[cur][0] + r * 32 + sl * 8);
        }
#pragma unroll
        for (int j = 0; j < FN; ++j) {
            int r = j * 16 + l16;
            int sl = quad ^ ((r >> 1) & 3);
            bf[j] = *(const short8*)(&Bs[cur][0] + r * 32 + sl * 8);
        }
#pragma unroll
        for (int i = 0; i < FM; ++i)
#pragma unroll
            for (int j = 0; j < FN; ++j)
                acc[i][j] = __builtin_amdgcn_mfma_f32_16x16x32_bf16(a[i], bf[j], acc[i][j], 0, 0, 0);
        if (hn) *(short8*)(cur ? bl0 : bl1) = packB(v0, v1);
        __syncthreads();
        cur ^= 1;
    }
    // epilogue: full contiguous row spans (complete cache lines)
    float* Cp = Cpart + (size_t)blockIdx.z * BM * N;
#pragma unroll
    for (int i = 0; i < FM; ++i)
#pragma unroll
        for (int rr = 0; rr < 4; ++rr) {
            int row = wave * 64 + i * 16 + quad * 4 + rr;
            float* cr = Cp + (size_t)row * N + n0;
#pragma unroll
            for (int j = 0; j < FN; ++j)
                cr[j * 16 + l16] = acc[i][j][rr];
        }
}

// ---------------- reduce over Z + bias + relu + bf16 cast (G1/G4) -----------
__global__ __launch_bounds__(256) void reduce_bias(
        const float* __restrict__ part, int zc, int mn4,
        const float* __restrict__ bias, int nmask, int relu,
        unsigned short* __restrict__ obf, float* __restrict__ of) {
    int idx = blockIdx.x * 256 + threadIdx.x;    // float4 index
    if (idx >= mn4) return;
    int idx4 = idx * 4;
    const float* bp = bias + (idx4 & nmask);
    float4 acc = *(const float4*)bp;
    const float4* p = (const float4*)part + idx;
    for (int z = 0; z < zc; ++z) {
        float4 v = p[(size_t)z * mn4];
        acc.x += v.x; acc.y += v.y; acc.z += v.z; acc.w += v.w;
    }
    if (relu) {
        acc.x = fmaxf(acc.x, 0.f); acc.y = fmaxf(acc.y, 0.f);
        acc.z = fmaxf(acc.z, 0.f); acc.w = fmaxf(acc.w, 0.f);
    }
    if (obf) {
        ushort4 h;
        h.x = f2bf(acc.x); h.y = f2bf(acc.y); h.z = f2bf(acc.z); h.w = f2bf(acc.w);
        *(ushort4*)(obf + idx4) = h;
    }
    if (of) *(float4*)(of + idx4) = acc;
}

// ---- G2-reduce + G3 fused: off = relu(red(part)+b2) @ w3^T + b3 ------------
__global__ __launch_bounds__(256) void fc_small_red(
        const float* __restrict__ part, int zc,
        const float* __restrict__ b2, const float* __restrict__ w3,
        const float* __restrict__ b3, float* __restrict__ out) {
    __shared__ float shl[2][1024];
    int n2 = blockIdx.x * 2;
    int tid = threadIdx.x;
    for (int i = tid; i < 2048; i += 256) {
        int n = n2 + (i >> 10), k = i & 1023;
        float acc = b2[k];
        for (int z = 0; z < zc; ++z)
            acc += part[(size_t)z * (NROI * DFC) + n * 1024 + k];
        shl[i >> 10][k] = fmaxf(acc, 0.f);
    }
    __syncthreads();
    int h = tid >> 7, o = tid & 127;
    if (o < 98) {
        float acc = b3[o];
        const float* w = w3 + (size_t)o * 1024;
        const float* s = shl[h];
        for (int k = 0; k < 1024; k += 4) {
            float4 wv = *(const float4*)(w + k);
            acc += s[k] * wv.x + s[k + 1] * wv.y + s[k + 2] * wv.z + s[k + 3] * wv.w;
        }
        out[(n2 + h) * 98 + o] = acc;
    }
}

// ---- G5-reduce + head fused: out = relu(red(part)+fc2_b) @ box_w^T + bb ----
__global__ __launch_bounds__(64) void head_red(
        const float* __restrict__ part, int zc,
        const float* __restrict__ b4, const float* __restrict__ bw,
        const float* __restrict__ bb, float* __restrict__ out) {
    int n = blockIdx.x, t = threadIdx.x;
    float a0 = 0, a1 = 0, a2 = 0, a3 = 0;
    for (int k = t; k < 512; k += 64) {
        float acc = b4[k];
        for (int z = 0; z < zc; ++z)
            acc += part[(size_t)z * (NROI * FCC) + n * 512 + k];
        float v = fmaxf(acc, 0.f);
        a0 += v * bw[k]; a1 += v * bw[512 + k];
        a2 += v * bw[1024 + k]; a3 += v * bw[1536 + k];
    }
#pragma unroll
    for (int o = 32; o > 0; o >>= 1) {
        a0 += __shfl_down(a0, o); a1 += __shfl_down(a1, o);
        a2 += __shfl_down(a2, o); a3 += __shfl_down(a3, o);
    }
    if (t == 0) {
        out[n * 4 + 0] = a0 + bb[0]; out[n * 4 + 1] = a1 + bb[1];
        out[n * 4 + 2] = a2 + bb[2]; out[n * 4 + 3] = a3 + bb[3];
    }
}

// ---------------------------------------------------------------------------
extern "C" void kernel_launch(void* const* d_in, const int* in_sizes, int n_in,
                              void* d_out, int out_size, void* d_ws, size_t ws_size,
                              hipStream_t stream) {
    const float* x      = (const float*)d_in[0];
    const float* rois   = (const float*)d_in[1];
    const float* off_w1 = (const float*)d_in[2];
    const float* off_b1 = (const float*)d_in[3];
    const float* off_w2 = (const float*)d_in[4];
    const float* off_b2 = (const float*)d_in[5];
    const float* off_w3 = (const float*)d_in[6];
    const float* off_b3 = (const float*)d_in[7];
    const float* fc1_w  = (const float*)d_in[8];
    const float* fc1_b  = (const float*)d_in[9];
    const float* fc2_w  = (const float*)d_in[10];
    const float* fc2_b  = (const float*)d_in[11];
    const float* box_w  = (const float*)d_in[12];
    const float* box_b  = (const float*)d_in[13];
    float* out = (float*)d_out;

    char* ws = (char*)d_ws;
    size_t o = 0;
    auto carve = [&](size_t bytes) { char* p = ws + o; o += (bytes + 255) & ~(size_t)255; return p; };
    float*          xT   = (float*)carve((size_t)NB * 625 * 256 * 4);   // 5.12 MB
    unsigned short* P    = (unsigned short*)carve((size_t)NROI * INF * 2); // shared p0/p1
    unsigned short* h1b  = (unsigned short*)carve((size_t)NROI * DFC * 2);
    float*          offb = (float*)carve((size_t)NROI * 98 * 4);
    unsigned short* h3b  = (unsigned short*)carve((size_t)NROI * FCC * 2);
    size_t fixed = o;
    const size_t SLAB = (size_t)NROI * DFC * 4;   // 1 MB (G1/G2-sized slice)
    int zg1;                        // tier on ws_size (constant -> graph-safe)
    if      (ws_size >= fixed + 28 * SLAB) zg1 = 28;
    else if (ws_size >= fixed + 14 * SLAB) zg1 = 14;
    else                                   zg1 = 7;
    int zg4 = zg1 * 2;              // G4 slabs are half-size (N=512)
    float* part = (float*)carve((size_t)zg1 * SLAB);

    // 1. channels-last transpose of x
    transpose_kernel<<<dim3(20, 8, 8), 256, 0, stream>>>(x, xT);
    // 2. pool pass 0 (zero offsets), prep fused
    pool_kernel<<<dim3(2, NROI), 256, 0, stream>>>(xT, rois, nullptr, 0, P);
    // 3. G1 partials + reduce(+b1+relu) -> h1b     (256x12544x1024)
    gemm_pipe<<<dim3(16, 1, zg1), 256, 0, stream>>>(P, off_w1, part, DFC, INF, 392 / zg1);
    reduce_bias<<<256, 256, 0, stream>>>(part, zg1, NROI * DFC / 4, off_b1, DFC - 1, 1, h1b, nullptr);
    // 4. G2 partials (256x1024x1024, z=8)
    gemm_pipe<<<dim3(16, 1, 8), 256, 0, stream>>>(h1b, off_w2, part, DFC, DFC, 4);
    // 5. fused G2-reduce + G3: offb = relu(red+b2) @ w3^T + b3
    fc_small_red<<<128, 256, 0, stream>>>(part, 8, off_b2, off_w3, off_b3, offb);
    // 6. pool pass 1 (learned offsets), reuses P
    pool_kernel<<<dim3(2, NROI), 256, 0, stream>>>(xT, rois, offb, 1, P);
    // 7. G4 partials + reduce(+fc1_b+relu) -> h3b  (256x12544x512)
    gemm_pipe<<<dim3(8, 1, zg4), 256, 0, stream>>>(P, fc1_w, part, FCC, INF, 392 / zg4);
    reduce_bias<<<128, 256, 0, stream>>>(part, zg4, NROI * FCC / 4, fc1_b, FCC - 1, 1, h3b, nullptr);
    // 8. G5 partials (256x512x512, z=8)
    gemm_pipe<<<dim3(8, 1, 8), 256, 0, stream>>>(h3b, fc2_w, part, FCC, FCC, 2);
    // 9. fused G5-reduce + head: out = relu(red+fc2_b) @ box_w^T + box_b
    head_red<<<NROI, 64, 0, stream>>>(part, 8, fc2_b, box_w, box_b, out);
}

// Round 5
// 288.794 us; speedup vs baseline: 1.0732x; 1.0732x over previous
//
#include <hip/hip_runtime.h>
#include <hip/hip_bf16.h>

// ---------------------------------------------------------------------------
// FCx2DetHead pipeline. R12:
//  - fc_small_red rewritten wave-parallel: R11 counters showed it at 44us,
//    Occ 5%, VALU 3% -- a serial 256-iter loop on 196 threads. Now 1 block
//    per roi, wave per output o, 64 lanes split K=1024 (16 stride-64 mults),
//    shfl reduce. Predicted <10us.
//  - gemm_pipe reverted to the R10-measured config (B fp32 via
//    global_load_lds, f2bf at consume): R11's B reg-staging coincided with
//    +19us total; R10's 2-phase loop is the best-measured gemm.
//  - Fusions kept: reduce(G2)+G3 -> fc_small_red, reduce(G5)+head -> head_red.
// ---------------------------------------------------------------------------

#define NROI 256
#define NB   8
#define INF  12544   // 256*49
#define DFC  1024
#define FCC  512

typedef __attribute__((ext_vector_type(8))) short short8;
typedef __attribute__((ext_vector_type(4))) float floatx4;

static __device__ __forceinline__ unsigned short f2bf(float f) {
    unsigned int u = __float_as_uint(f);
    unsigned int r = (u + 0x7fffu + ((u >> 16) & 1u)) >> 16;
    return (unsigned short)r;
}

static __device__ __forceinline__ void async_copy16(const void* g, void* l) {
    __builtin_amdgcn_global_load_lds(
        (const __attribute__((address_space(1))) unsigned int*)g,
        (__attribute__((address_space(3))) unsigned int*)l, 16, 0, 0);
}

// ---------------- transpose x (B,C,H,W) -> feat (B,H,W,C) -------------------
__global__ __launch_bounds__(256) void transpose_kernel(
        const float* __restrict__ x, float* __restrict__ xT) {
    __shared__ float t[32][33];
    int b  = blockIdx.z;
    int cb = blockIdx.y * 32;     // channel tile
    int lb = blockIdx.x * 32;     // hw tile (0..624)
    int tx = threadIdx.x & 31, ty = threadIdx.x >> 5;
#pragma unroll
    for (int r = 0; r < 4; ++r) {
        int c = cb + ty + r * 8, l = lb + tx;
        if (l < 625) t[ty + r * 8][tx] = x[(size_t)(b * 256 + c) * 625 + l];
    }
    __syncthreads();
#pragma unroll
    for (int r = 0; r < 4; ++r) {
        int l = lb + ty + r * 8, c = cb + tx;
        if (l < 625) xT[((size_t)b * 625 + l) * 256 + c] = t[tx][ty + r * 8];
    }
}

// ---------------- fused deformable RoI pool (prep + gather) -----------------
__global__ __launch_bounds__(256) void pool_kernel(
        const float* __restrict__ feat, const float* __restrict__ rois,
        const float* __restrict__ off, int has_off,
        unsigned short* __restrict__ P) {
    __shared__ float sGrid[49][16];
    __shared__ int   sBase[49];
    __shared__ unsigned short sOut[128 * 49];
    const float SSC = (float)(25.0 / 255.0);
    int q = blockIdx.x;            // channel half
    int n = blockIdx.y;            // roi
    int tid = threadIdx.x;

    if (tid < 49) {
        int bin = tid;
        const float* r = rois + n * 5;
        int b = (int)r[0];
        float sw = rintf(r[1]) * SSC - 0.5f;
        float sh = rintf(r[2]) * SSC - 0.5f;
        float rw = fmaxf((rintf(r[3]) + 1.0f) * SSC - 0.5f - sw, 0.1f);
        float rh = fmaxf((rintf(r[4]) + 1.0f) * SSC - 0.5f - sh, 0.1f);
        float bw = rw / 7.0f, bh = rh / 7.0f;
        float bws = bw * 0.25f, bhs = bh * 0.25f;
        int ph = bin / 7, pw = bin - ph * 7;
        float tx = 0.f, ty = 0.f;
        if (has_off) {
            tx = off[n * 98 + bin] * 0.1f;
            ty = off[n * 98 + 49 + bin] * 0.1f;
        }
        float wstart = pw * bw + sw + tx * rw;
        float hstart = ph * bh + sh + ty * rh;
#pragma unroll
        for (int i = 0; i < 16; ++i) sGrid[bin][i] = 0.f;
        int gy0 = 0, gx0 = 0, cnt = 0;
#pragma unroll
        for (int s = 0; s < 16; ++s) {
            float fx = wstart + (s & 3) * bws;
            float fy = hstart + (s >> 2) * bhs;
            bool valid = (fx >= -0.5f) && (fx <= 24.5f) && (fy >= -0.5f) && (fy <= 24.5f);
            float xc = fminf(fmaxf(fx, 0.f), 24.f);
            float yc = fminf(fmaxf(fy, 0.f), 24.f);
            float x0f = floorf(xc), y0f = floorf(yc);
            float dx = xc - x0f, dy = yc - y0f;
            int x0 = (int)x0f, y0 = (int)y0f;
            int x1 = (int)ceilf(xc), y1 = (int)ceilf(yc);
            if (s == 0) { gy0 = y0; gx0 = x0; }
            float w00 = (1.f - dx) * (1.f - dy), w01 = dx * (1.f - dy);
            float w10 = (1.f - dx) * dy,         w11 = dx * dy;
            if (!valid) { w00 = w01 = w10 = w11 = 0.f; }
            cnt += valid ? 1 : 0;
            int ry0 = (y0 - gy0) * 4, ry1 = (y1 - gy0) * 4;
            sGrid[bin][ry0 + (x0 - gx0)] += w00;
            sGrid[bin][ry0 + (x1 - gx0)] += w01;
            sGrid[bin][ry1 + (x0 - gx0)] += w10;
            sGrid[bin][ry1 + (x1 - gx0)] += w11;
        }
        float inv = 1.0f / fmaxf((float)cnt, 1.0f);
#pragma unroll
        for (int i = 0; i < 16; ++i) sGrid[bin][i] *= inv;
        sBase[bin] = gy0 | (gx0 << 8) | (b << 16);
    }
    __syncthreads();

    int wv = tid >> 6, lane = tid & 63;
    int cbase = q * 128 + lane * 2;
    for (int bin = wv; bin < 49; bin += 4) {
        int base = sBase[bin];
        int gy0 = base & 255, gx0 = (base >> 8) & 255, b = base >> 16;
        const float4* wp = (const float4*)sGrid[bin];
        float4 w0 = wp[0], w1 = wp[1], w2 = wp[2], w3 = wp[3];
        float ww[16] = { w0.x, w0.y, w0.z, w0.w, w1.x, w1.y, w1.z, w1.w,
                         w2.x, w2.y, w2.z, w2.w, w3.x, w3.y, w3.z, w3.w };
        int rowOff[4], colOff[4];
#pragma unroll
        for (int r = 0; r < 4; ++r) {
            rowOff[r] = min(gy0 + r, 24) * 25;
            colOff[r] = min(gx0 + r, 24);
        }
        int b625 = b * 625;
        float ax = 0.f, ay = 0.f;
#pragma unroll
        for (int cell = 0; cell < 16; ++cell) {
            int pix = b625 + rowOff[cell >> 2] + colOff[cell & 3];
            float2 v = *(const float2*)(feat + (size_t)pix * 256 + cbase);
            ax += ww[cell] * v.x;
            ay += ww[cell] * v.y;
        }
        sOut[(lane * 2) * 49 + bin] = f2bf(ax);
        sOut[(lane * 2 + 1) * 49 + bin] = f2bf(ay);
    }
    __syncthreads();
    const uint2* so = (const uint2*)sOut;
    uint2* dp = (uint2*)(P + (size_t)n * INF + q * 128 * 49);
    for (int i = tid; i < 128 * 49 / 4; i += 256) dp[i] = so[i];
}

// ---------------- 2-phase MFMA GEMM (BM=256=M, BN=64) -> fp32 partials ------
// R10-measured config: STAGE(next buf) -> ds_read+MFMA(cur buf) ->
// __syncthreads. D=2, 48 KB LDS -> 3 blocks/CU. 6 global_load_lds per thread
// per k-step (4x A 16B bf16, 2x B 16B fp32), f2bf at consume.
// A swizzle: 16B-unit kg4 ^= (row>>1)&3. B swizzle: kg ^= (row>>1)&7.
__global__ __launch_bounds__(256) void gemm_pipe(
        const unsigned short* __restrict__ A, const float* __restrict__ Bw,
        float* __restrict__ Cpart, int N, int K, int kSteps) {
    constexpr int BM = 256, BN = 64;
    constexpr int FM = 4, FN = 4;
    __shared__ unsigned short As[2][BM * 32];  // 16 KB / slot
    __shared__ float          Bs[2][BN * 32];  //  8 KB / slot
    const int tid = threadIdx.x;
    const int lane = tid & 63;
    const int wave = tid >> 6;
    const int n0 = blockIdx.x * BN;
    const int k0 = blockIdx.z * kSteps * 32;
    const int quad = lane >> 4;
    const int l16 = lane & 15;

    floatx4 acc[FM][FN];
#pragma unroll
    for (int i = 0; i < FM; ++i)
#pragma unroll
        for (int j = 0; j < FN; ++j) acc[i][j] = (floatx4)0.f;

    // A staging: thread t, copy i -> LDS 16B-unit (i*256 + t)
    const unsigned short* ag[4];
    int albase[4];
#pragma unroll
    for (int i = 0; i < 4; ++i) {
        int idx = tid + i * 256;
        int row = idx >> 2;
        int kg4 = (idx & 3) ^ ((row >> 1) & 3);
        ag[i] = A + (size_t)row * K + kg4 * 8;
        albase[i] = (i * 256 + wave * 64) * 16;   // wave-uniform byte base
    }
    // B staging: thread t, copy i -> LDS 16B-unit (i*256 + t); 512 units
    const float* bg[2];
    int blbase[2];
#pragma unroll
    for (int i = 0; i < 2; ++i) {
        int idx = tid + i * 256;
        int row = idx >> 3;
        int kg = (idx & 7) ^ ((row >> 1) & 7);
        bg[i] = Bw + (size_t)(n0 + row) * K + kg * 4;
        blbase[i] = (i * 256 + wave * 64) * 16;
    }

    auto issue = [&](int slot, int kk) {
#pragma unroll
        for (int i = 0; i < 4; ++i)
            async_copy16(ag[i] + kk, (char*)&As[slot][0] + albase[i]);
#pragma unroll
        for (int i = 0; i < 2; ++i)
            async_copy16(bg[i] + kk, (char*)&Bs[slot][0] + blbase[i]);
    };

    // prologue: stage k-step 0 into slot 0; __syncthreads drains vmcnt
    issue(0, k0);
    __syncthreads();

    int cur = 0;
    for (int ks = 0; ks < kSteps; ++ks) {
        // stage next k-step into the other slot (issued before compute;
        // the end-of-iter __syncthreads drains it before it is consumed)
        if (ks + 1 < kSteps) issue(cur ^ 1, k0 + (ks + 1) * 32);
        // fragments from slot cur
        short8 a[FM], bf[FN];
#pragma unroll
        for (int i = 0; i < FM; ++i) {
            int r = wave * 64 + i * 16 + l16;
            int sl = quad ^ ((r >> 1) & 3);
            a[i] = *(const short8*)(&As[cur][0] + r * 32 + sl * 8);
        }
#pragma unroll
        for (int j = 0; j < FN; ++j) {
            int r = j * 16 + l16;
            int sw8 = (r >> 1) & 7;
            int g0 = (quad * 2) ^ sw8;
            int g1 = (quad * 2 + 1) ^ sw8;
            float4 v0 = *(const float4*)(&Bs[cur][0] + r * 32 + g0 * 4);
            float4 v1 = *(const float4*)(&Bs[cur][0] + r * 32 + g1 * 4);
            bf[j][0] = (short)f2bf(v0.x); bf[j][1] = (short)f2bf(v0.y);
            bf[j][2] = (short)f2bf(v0.z); bf[j][3] = (short)f2bf(v0.w);
            bf[j][4] = (short)f2bf(v1.x); bf[j][5] = (short)f2bf(v1.y);
            bf[j][6] = (short)f2bf(v1.z); bf[j][7] = (short)f2bf(v1.w);
        }
#pragma unroll
        for (int i = 0; i < FM; ++i)
#pragma unroll
            for (int j = 0; j < FN; ++j)
                acc[i][j] = __builtin_amdgcn_mfma_f32_16x16x32_bf16(a[i], bf[j], acc[i][j], 0, 0, 0);
        __syncthreads();
        cur ^= 1;
    }
    // epilogue: full contiguous row spans (complete cache lines)
    float* Cp = Cpart + (size_t)blockIdx.z * BM * N;
#pragma unroll
    for (int i = 0; i < FM; ++i)
#pragma unroll
        for (int rr = 0; rr < 4; ++rr) {
            int row = wave * 64 + i * 16 + quad * 4 + rr;
            float* cr = Cp + (size_t)row * N + n0;
#pragma unroll
            for (int j = 0; j < FN; ++j)
                cr[j * 16 + l16] = acc[i][j][rr];
        }
}

// ---------------- reduce over Z + bias + relu + bf16 cast (G1/G4) -----------
__global__ __launch_bounds__(256) void reduce_bias(
        const float* __restrict__ part, int zc, int mn4,
        const float* __restrict__ bias, int nmask, int relu,
        unsigned short* __restrict__ obf, float* __restrict__ of) {
    int idx = blockIdx.x * 256 + threadIdx.x;    // float4 index
    if (idx >= mn4) return;
    int idx4 = idx * 4;
    const float* bp = bias + (idx4 & nmask);
    float4 acc = *(const float4*)bp;
    const float4* p = (const float4*)part + idx;
    for (int z = 0; z < zc; ++z) {
        float4 v = p[(size_t)z * mn4];
        acc.x += v.x; acc.y += v.y; acc.z += v.z; acc.w += v.w;
    }
    if (relu) {
        acc.x = fmaxf(acc.x, 0.f); acc.y = fmaxf(acc.y, 0.f);
        acc.z = fmaxf(acc.z, 0.f); acc.w = fmaxf(acc.w, 0.f);
    }
    if (obf) {
        ushort4 h;
        h.x = f2bf(acc.x); h.y = f2bf(acc.y); h.z = f2bf(acc.z); h.w = f2bf(acc.w);
        *(ushort4*)(obf + idx4) = h;
    }
    if (of) *(float4*)(of + idx4) = acc;
}

// ---- G2-reduce + G3 fused, wave-parallel: off = relu(red+b2) @ w3^T + b3 ---
// 1 block per roi. Phase 1: 256 threads reduce z slabs (float4 each), relu,
// -> LDS s[1024]. Phase 2: wave per output o (4 concurrent), 64 lanes split
// K=1024 as k = lane + 64*i (coalesced w3 reads, 2-way-free LDS banks),
// 16 FMA + 6-step shfl reduce.
__global__ __launch_bounds__(256) void fc_small_red(
        const float* __restrict__ part, int zc,
        const float* __restrict__ b2, const float* __restrict__ w3,
        const float* __restrict__ b3, float* __restrict__ out) {
    __shared__ float s[1024];
    int n = blockIdx.x;
    int tid = threadIdx.x;
    float4 a4 = *(const float4*)(b2 + tid * 4);
    const float* pb = part + (size_t)n * 1024 + tid * 4;
    for (int z = 0; z < zc; ++z) {
        float4 v = *(const float4*)(pb + (size_t)z * (NROI * DFC));
        a4.x += v.x; a4.y += v.y; a4.z += v.z; a4.w += v.w;
    }
    a4.x = fmaxf(a4.x, 0.f); a4.y = fmaxf(a4.y, 0.f);
    a4.z = fmaxf(a4.z, 0.f); a4.w = fmaxf(a4.w, 0.f);
    *(float4*)(s + tid * 4) = a4;
    __syncthreads();
    int wv = tid >> 6, lane = tid & 63;
    for (int o = wv; o < 98; o += 4) {
        const float* w = w3 + (size_t)o * 1024 + lane;
        float a = 0.f;
#pragma unroll
        for (int i = 0; i < 16; ++i)
            a += w[i * 64] * s[lane + i * 64];
#pragma unroll
        for (int off = 32; off > 0; off >>= 1) a += __shfl_down(a, off);
        if (lane == 0) out[n * 98 + o] = b3[o] + a;
    }
}

// ---- G5-reduce + head fused: out = relu(red(part)+fc2_b) @ box_w^T + bb ----
__global__ __launch_bounds__(64) void head_red(
        const float* __restrict__ part, int zc,
        const float* __restrict__ b4, const float* __restrict__ bw,
        const float* __restrict__ bb, float* __restrict__ out) {
    int n = blockIdx.x, t = threadIdx.x;
    float a0 = 0, a1 = 0, a2 = 0, a3 = 0;
    for (int k = t; k < 512; k += 64) {
        float acc = b4[k];
        for (int z = 0; z < zc; ++z)
            acc += part[(size_t)z * (NROI * FCC) + n * 512 + k];
        float v = fmaxf(acc, 0.f);
        a0 += v * bw[k]; a1 += v * bw[512 + k];
        a2 += v * bw[1024 + k]; a3 += v * bw[1536 + k];
    }
#pragma unroll
    for (int o = 32; o > 0; o >>= 1) {
        a0 += __shfl_down(a0, o); a1 += __shfl_down(a1, o);
        a2 += __shfl_down(a2, o); a3 += __shfl_down(a3, o);
    }
    if (t == 0) {
        out[n * 4 + 0] = a0 + bb[0]; out[n * 4 + 1] = a1 + bb[1];
        out[n * 4 + 2] = a2 + bb[2]; out[n * 4 + 3] = a3 + bb[3];
    }
}

// ---------------------------------------------------------------------------
extern "C" void kernel_launch(void* const* d_in, const int* in_sizes, int n_in,
                              void* d_out, int out_size, void* d_ws, size_t ws_size,
                              hipStream_t stream) {
    const float* x      = (const float*)d_in[0];
    const float* rois   = (const float*)d_in[1];
    const float* off_w1 = (const float*)d_in[2];
    const float* off_b1 = (const float*)d_in[3];
    const float* off_w2 = (const float*)d_in[4];
    const float* off_b2 = (const float*)d_in[5];
    const float* off_w3 = (const float*)d_in[6];
    const float* off_b3 = (const float*)d_in[7];
    const float* fc1_w  = (const float*)d_in[8];
    const float* fc1_b  = (const float*)d_in[9];
    const float* fc2_w  = (const float*)d_in[10];
    const float* fc2_b  = (const float*)d_in[11];
    const float* box_w  = (const float*)d_in[12];
    const float* box_b  = (const float*)d_in[13];
    float* out = (float*)d_out;

    char* ws = (char*)d_ws;
    size_t o = 0;
    auto carve = [&](size_t bytes) { char* p = ws + o; o += (bytes + 255) & ~(size_t)255; return p; };
    float*          xT   = (float*)carve((size_t)NB * 625 * 256 * 4);   // 5.12 MB
    unsigned short* P    = (unsigned short*)carve((size_t)NROI * INF * 2); // shared p0/p1
    unsigned short* h1b  = (unsigned short*)carve((size_t)NROI * DFC * 2);
    float*          offb = (float*)carve((size_t)NROI * 98 * 4);
    unsigned short* h3b  = (unsigned short*)carve((size_t)NROI * FCC * 2);
    size_t fixed = o;
    const size_t SLAB = (size_t)NROI * DFC * 4;   // 1 MB (G1/G2-sized slice)
    int zg1;                        // tier on ws_size (constant -> graph-safe)
    if      (ws_size >= fixed + 28 * SLAB) zg1 = 28;
    else if (ws_size >= fixed + 14 * SLAB) zg1 = 14;
    else                                   zg1 = 7;
    int zg4 = zg1 * 2;              // G4 slabs are half-size (N=512)
    float* part = (float*)carve((size_t)zg1 * SLAB);

    // 1. channels-last transpose of x
    transpose_kernel<<<dim3(20, 8, 8), 256, 0, stream>>>(x, xT);
    // 2. pool pass 0 (zero offsets), prep fused
    pool_kernel<<<dim3(2, NROI), 256, 0, stream>>>(xT, rois, nullptr, 0, P);
    // 3. G1 partials + reduce(+b1+relu) -> h1b     (256x12544x1024)
    gemm_pipe<<<dim3(16, 1, zg1), 256, 0, stream>>>(P, off_w1, part, DFC, INF, 392 / zg1);
    reduce_bias<<<256, 256, 0, stream>>>(part, zg1, NROI * DFC / 4, off_b1, DFC - 1, 1, h1b, nullptr);
    // 4. G2 partials (256x1024x1024, z=8)
    gemm_pipe<<<dim3(16, 1, 8), 256, 0, stream>>>(h1b, off_w2, part, DFC, DFC, 4);
    // 5. fused G2-reduce + G3: offb = relu(red+b2) @ w3^T + b3
    fc_small_red<<<NROI, 256, 0, stream>>>(part, 8, off_b2, off_w3, off_b3, offb);
    // 6. pool pass 1 (learned offsets), reuses P
    pool_kernel<<<dim3(2, NROI), 256, 0, stream>>>(xT, rois, offb, 1, P);
    // 7. G4 partials + reduce(+fc1_b+relu) -> h3b  (256x12544x512)
    gemm_pipe<<<dim3(8, 1, zg4), 256, 0, stream>>>(P, fc1_w, part, FCC, INF, 392 / zg4);
    reduce_bias<<<128, 256, 0, stream>>>(part, zg4, NROI * FCC / 4, fc1_b, FCC - 1, 1, h3b, nullptr);
    // 8. G5 partials (256x512x512, z=8)
    gemm_pipe<<<dim3(8, 1, 8), 256, 0, stream>>>(h3b, fc2_w, part, FCC, FCC, 2);
    // 9. fused G5-reduce + head: out = relu(red+fc2_b) @ box_w^T + box_b
    head_red<<<NROI, 64, 0, stream>>>(part, 8, fc2_b, box_w, box_b, out);
}